// Round 1
// baseline (23302.348 us; speedup 1.0000x reference)
//
#include <hip/hip_runtime.h>
#include <math.h>

#define EMBED  64
#define HIDDEN 256
#define SEQ    200
#define SPAD   204   // hT row stride: 16B-aligned float4 reads, breaks pow2 bank stride

__global__ __launch_bounds__(256, 2)
void din_fused_kernel(const int* __restrict__ user_hist,
                      const int* __restrict__ target_item,
                      const float* __restrict__ user_emb,
                      const float* __restrict__ item_emb,
                      const float* __restrict__ attn_w1,
                      const float* __restrict__ attn_b1,
                      const float* __restrict__ attn_w2,
                      const float* __restrict__ mlp_w1,
                      const float* __restrict__ mlp_b1,
                      const float* __restrict__ mlp_w2,
                      const float* __restrict__ mlp_b2,
                      float* __restrict__ out)
{
  __shared__ __align__(16) float hT[EMBED * SPAD];   // 52224 B, transposed h
  __shared__ float t_s[EMBED];
  __shared__ float logits[SEQ];
  __shared__ float weights[SEQ];
  __shared__ float red[8];
  __shared__ float interest_part[4][EMBED];
  __shared__ float mlp_in[2 * EMBED];

  const int b    = blockIdx.x;
  const int tid  = threadIdx.x;
  const int lane = tid & 63;
  const int wave = tid >> 6;

  // ---- phase 0: target embedding + zero logits ----
  if (tid < EMBED) {
    const int tgt = target_item[b];
    t_s[tid] = item_emb[tgt * EMBED + tid];
  }
  if (tid < SEQ) logits[tid] = 0.0f;
  __syncthreads();

  // ---- phase 1: per-thread effective attention weight column (j = tid) ----
  // hidden_j(s) = sum_k h_s[k] * Weff[k] + c_j   (K reduced 256 -> 64)
  const int j = tid;
  float Weff[EMBED];
  float cj = attn_b1[j];
  #pragma unroll
  for (int k = 0; k < EMBED; ++k) {
    const float tk = t_s[k];
    const float a0 = attn_w1[(0 * EMBED + k) * HIDDEN + j];
    const float a1 = attn_w1[(1 * EMBED + k) * HIDDEN + j];
    const float a2 = attn_w1[(2 * EMBED + k) * HIDDEN + j];
    const float a3 = attn_w1[(3 * EMBED + k) * HIDDEN + j];
    Weff[k] = a0 + a2 + tk * a3;
    cj += tk * (a1 - a2);
  }
  const float w2j = attn_w2[j];

  // ---- phase 2: gather history embeddings into transposed LDS tile ----
  const int* hist = user_hist + b * SEQ;
  for (int idx = tid; idx < SEQ * (EMBED / 4); idx += 256) {
    const int s = idx >> 4;
    const int q = idx & 15;
    const int row = hist[s];
    const float4 hv = *reinterpret_cast<const float4*>(&user_emb[row * EMBED + q * 4]);
    hT[(4 * q + 0) * SPAD + s] = hv.x;
    hT[(4 * q + 1) * SPAD + s] = hv.y;
    hT[(4 * q + 2) * SPAD + s] = hv.z;
    hT[(4 * q + 3) * SPAD + s] = hv.w;
  }
  __syncthreads();

  // ---- phase 3: attention MLP (K=64 GEMM) + logits ----
  for (int s0 = 0; s0 < SEQ; s0 += 8) {
    float acc[8];
    #pragma unroll
    for (int i = 0; i < 8; ++i) acc[i] = cj;
    #pragma unroll
    for (int k = 0; k < EMBED; ++k) {
      const float w = Weff[k];
      const float4* p = reinterpret_cast<const float4*>(&hT[k * SPAD + s0]);
      const float4 a = p[0];   // broadcast ds_read_b128 (all lanes same addr)
      const float4 d = p[1];
      acc[0] += a.x * w;  acc[1] += a.y * w;
      acc[2] += a.z * w;  acc[3] += a.w * w;
      acc[4] += d.x * w;  acc[5] += d.y * w;
      acc[6] += d.z * w;  acc[7] += d.w * w;
    }
    #pragma unroll
    for (int i = 0; i < 8; ++i) {
      float p = fmaxf(acc[i], 0.0f) * w2j;
      #pragma unroll
      for (int off = 32; off; off >>= 1) p += __shfl_xor(p, off, 64);
      if (lane == 0) atomicAdd(&logits[s0 + i], p);
    }
  }
  __syncthreads();

  // ---- phase 4: softmax over SEQ (attn_b2 cancels) ----
  float v = (tid < SEQ) ? logits[tid] : -INFINITY;
  float m = v;
  #pragma unroll
  for (int off = 32; off; off >>= 1) m = fmaxf(m, __shfl_xor(m, off, 64));
  if (lane == 0) red[wave] = m;
  __syncthreads();
  m = fmaxf(fmaxf(red[0], red[1]), fmaxf(red[2], red[3]));
  float e = (tid < SEQ) ? expf(v - m) : 0.0f;
  float ssum = e;
  #pragma unroll
  for (int off = 32; off; off >>= 1) ssum += __shfl_xor(ssum, off, 64);
  if (lane == 0) red[4 + wave] = ssum;
  __syncthreads();
  const float tot = red[4] + red[5] + red[6] + red[7];
  if (tid < SEQ) weights[tid] = e / tot;
  __syncthreads();

  // ---- phase 5: weighted interest pooling ----
  {
    const int k = tid & 63;
    const int part = tid >> 6;
    float acc = 0.0f;
    for (int s = part * 50; s < part * 50 + 50; ++s)
      acc += weights[s] * hT[k * SPAD + s];
    interest_part[part][k] = acc;
  }
  __syncthreads();
  if (tid < EMBED) {
    mlp_in[tid] = interest_part[0][tid] + interest_part[1][tid]
                + interest_part[2][tid] + interest_part[3][tid];
    mlp_in[EMBED + tid] = t_s[tid];
  }
  __syncthreads();

  // ---- phase 6: prediction head ----
  float acc2 = mlp_b1[j];
  #pragma unroll
  for (int k = 0; k < 2 * EMBED; ++k)
    acc2 += mlp_in[k] * mlp_w1[k * HIDDEN + j];
  float p2 = fmaxf(acc2, 0.0f) * mlp_w2[j];
  #pragma unroll
  for (int off = 32; off; off >>= 1) p2 += __shfl_xor(p2, off, 64);
  if (lane == 0) red[wave] = p2;
  __syncthreads();
  if (tid == 0) {
    const float z = red[0] + red[1] + red[2] + red[3] + mlp_b2[0];
    out[b] = 1.0f / (1.0f + expf(-z));
  }
}

extern "C" void kernel_launch(void* const* d_in, const int* in_sizes, int n_in,
                              void* d_out, int out_size, void* d_ws, size_t ws_size,
                              hipStream_t stream) {
  const int*   user_hist   = (const int*)  d_in[0];
  const int*   target_item = (const int*)  d_in[1];
  const float* user_emb    = (const float*)d_in[2];
  const float* item_emb    = (const float*)d_in[3];
  const float* attn_w1     = (const float*)d_in[4];
  const float* attn_b1     = (const float*)d_in[5];
  const float* attn_w2     = (const float*)d_in[6];
  // d_in[7] = attn_b2: adds a constant to every logit -> cancels in softmax
  const float* mlp_w1      = (const float*)d_in[8];
  const float* mlp_b1      = (const float*)d_in[9];
  const float* mlp_w2      = (const float*)d_in[10];
  const float* mlp_b2      = (const float*)d_in[11];
  float* out = (float*)d_out;

  const int batch = in_sizes[1];   // target_item has BATCH elements
  din_fused_kernel<<<batch, 256, 0, stream>>>(
      user_hist, target_item, user_emb, item_emb,
      attn_w1, attn_b1, attn_w2,
      mlp_w1, mlp_b1, mlp_w2, mlp_b2, out);
}

// Round 2
// 512.285 us; speedup vs baseline: 45.4871x; 45.4871x over previous
//
#include <hip/hip_runtime.h>
#include <math.h>

#define EMBED  64
#define HIDDEN 256
#define SEQ    200
#define K2     32          // EMBED/2 (fp16 pairs along K)
#define SPAD2  204         // hP row stride in half2 units (16B-aligned rows)

typedef _Float16 half2_t __attribute__((ext_vector_type(2)));

__device__ inline float fdot2(half2_t a, half2_t b, float c) {
#if __has_builtin(__builtin_amdgcn_fdot2)
  return __builtin_amdgcn_fdot2(a, b, c, false);
#else
  return c + (float)a.x * (float)b.x + (float)a.y * (float)b.y;
#endif
}

__global__ __launch_bounds__(256, 2)
void din_fused_kernel(const int* __restrict__ user_hist,
                      const int* __restrict__ target_item,
                      const float* __restrict__ user_emb,
                      const float* __restrict__ item_emb,
                      const float* __restrict__ attn_w1,
                      const float* __restrict__ attn_b1,
                      const float* __restrict__ attn_w2,
                      const float* __restrict__ mlp_w1,
                      const float* __restrict__ mlp_b1,
                      const float* __restrict__ mlp_w2,
                      const float* __restrict__ mlp_b2,
                      float* __restrict__ out)
{
  // h history, transposed, fp16 pairs along K: hP[k2][s] = (h[2k2][s], h[2k2+1][s])
  __shared__ __align__(16) half2_t hP[K2 * SPAD2];        // 26112 B
  // effective attention W, fp16 pairs along K: Wl[(k2*64+lane)*4 + c] = col j=lane+64c
  __shared__ __align__(16) half2_t Wl[K2 * 64 * 4];       // 32768 B
  __shared__ float cl[HIDDEN];                            // per-column bias-fold
  __shared__ float t_s[EMBED];
  __shared__ float logits[SEQ];
  __shared__ float weights[SEQ];
  __shared__ float red[8];
  __shared__ float interest_part[4][EMBED];
  __shared__ float mlp_in[2 * EMBED];

  const int b    = blockIdx.x;
  const int tid  = threadIdx.x;
  const int lane = tid & 63;
  const int wave = tid >> 6;

  // ---- phase 0: target embedding ----
  if (tid < EMBED) {
    const int tgt = target_item[b];
    t_s[tid] = item_emb[tgt * EMBED + tid];
  }
  __syncthreads();

  // ---- phase 1: effective attention weights -> LDS (no private arrays) ----
  // hidden_j(s) = sum_k h_s[k]*Weff[k,j] + c_j, Weff = W0+W2+t_k*W3, c_j = b1 + sum t_k(W1-W2)
  {
    const int j = tid;
    float cj = attn_b1[j];
    #pragma unroll 4
    for (int k2 = 0; k2 < K2; ++k2) {
      const int k = 2 * k2;
      const float tk0 = t_s[k], tk1 = t_s[k + 1];
      const float a0 = attn_w1[(k      ) * HIDDEN + j];
      const float b0 = attn_w1[(64 + k ) * HIDDEN + j];
      const float c0 = attn_w1[(128 + k) * HIDDEN + j];
      const float d0 = attn_w1[(192 + k) * HIDDEN + j];
      const float a1 = attn_w1[(k + 1      ) * HIDDEN + j];
      const float b1 = attn_w1[(64 + k + 1 ) * HIDDEN + j];
      const float c1 = attn_w1[(128 + k + 1) * HIDDEN + j];
      const float d1 = attn_w1[(192 + k + 1) * HIDDEN + j];
      const float w0 = a0 + c0 + tk0 * d0;
      const float w1 = a1 + c1 + tk1 * d1;
      cj += tk0 * (b0 - c0) + tk1 * (b1 - c1);
      Wl[(k2 * 64 + (j & 63)) * 4 + (j >> 6)] = half2_t{(_Float16)w0, (_Float16)w1};
    }
    cl[j] = cj;
  }

  // ---- phase 2: gather history embeddings into fp16 LDS tile ----
  {
    const int* hist = user_hist + b * SEQ;
    for (int idx = tid; idx < SEQ * (EMBED / 4); idx += 256) {
      const int s = idx >> 4;
      const int q = idx & 15;
      const int row = hist[s];
      const float4 hv = *reinterpret_cast<const float4*>(&user_emb[row * EMBED + q * 4]);
      hP[(2 * q + 0) * SPAD2 + s] = half2_t{(_Float16)hv.x, (_Float16)hv.y};
      hP[(2 * q + 1) * SPAD2 + s] = half2_t{(_Float16)hv.z, (_Float16)hv.w};
    }
  }
  __syncthreads();

  // ---- phase 3: attention GEMM via v_dot2_f32_f16; each wave owns its s-tiles ----
  const float w2v0 = attn_w2[lane];
  const float w2v1 = attn_w2[lane + 64];
  const float w2v2 = attn_w2[lane + 128];
  const float w2v3 = attn_w2[lane + 192];
  const float ci0 = cl[lane];
  const float ci1 = cl[lane + 64];
  const float ci2 = cl[lane + 128];
  const float ci3 = cl[lane + 192];

  for (int tile = wave; tile < SEQ / 8; tile += 4) {
    const int s0 = tile * 8;
    float acc[4][8];
    #pragma unroll
    for (int si = 0; si < 8; ++si) {
      acc[0][si] = ci0; acc[1][si] = ci1; acc[2][si] = ci2; acc[3][si] = ci3;
    }
    #pragma unroll 4
    for (int k2 = 0; k2 < K2; ++k2) {
      const float4* hp4 = reinterpret_cast<const float4*>(&hP[k2 * SPAD2 + s0]);
      const float4 hA = hp4[0];          // broadcast: s0..s0+3 (half2 each)
      const float4 hB = hp4[1];          // broadcast: s0+4..s0+7
      const float4 wv = *reinterpret_cast<const float4*>(&Wl[(k2 * 64 + lane) * 4]);
      half2_t h2[8];
      h2[0] = __builtin_bit_cast(half2_t, hA.x);
      h2[1] = __builtin_bit_cast(half2_t, hA.y);
      h2[2] = __builtin_bit_cast(half2_t, hA.z);
      h2[3] = __builtin_bit_cast(half2_t, hA.w);
      h2[4] = __builtin_bit_cast(half2_t, hB.x);
      h2[5] = __builtin_bit_cast(half2_t, hB.y);
      h2[6] = __builtin_bit_cast(half2_t, hB.z);
      h2[7] = __builtin_bit_cast(half2_t, hB.w);
      half2_t wc[4];
      wc[0] = __builtin_bit_cast(half2_t, wv.x);
      wc[1] = __builtin_bit_cast(half2_t, wv.y);
      wc[2] = __builtin_bit_cast(half2_t, wv.z);
      wc[3] = __builtin_bit_cast(half2_t, wv.w);
      #pragma unroll
      for (int c = 0; c < 4; ++c)
        #pragma unroll
        for (int si = 0; si < 8; ++si)
          acc[c][si] = fdot2(h2[si], wc[c], acc[c][si]);
    }
    // epilogue: relu * w2, reduce over j (64 lanes x 4 cols), write logits
    #pragma unroll
    for (int si = 0; si < 8; ++si) {
      float v = fmaxf(acc[0][si], 0.0f) * w2v0
              + fmaxf(acc[1][si], 0.0f) * w2v1
              + fmaxf(acc[2][si], 0.0f) * w2v2
              + fmaxf(acc[3][si], 0.0f) * w2v3;
      #pragma unroll
      for (int off = 32; off; off >>= 1) v += __shfl_xor(v, off, 64);
      if (lane == 0) logits[s0 + si] = v;   // wave-private s-range: no atomic
    }
  }
  __syncthreads();

  // ---- phase 4: softmax over SEQ (attn_b2 cancels) ----
  float v = (tid < SEQ) ? logits[tid] : -INFINITY;
  float m = v;
  #pragma unroll
  for (int off = 32; off; off >>= 1) m = fmaxf(m, __shfl_xor(m, off, 64));
  if (lane == 0) red[wave] = m;
  __syncthreads();
  m = fmaxf(fmaxf(red[0], red[1]), fmaxf(red[2], red[3]));
  float e = (tid < SEQ) ? expf(v - m) : 0.0f;
  float ssum = e;
  #pragma unroll
  for (int off = 32; off; off >>= 1) ssum += __shfl_xor(ssum, off, 64);
  if (lane == 0) red[4 + wave] = ssum;
  __syncthreads();
  const float tot = red[4] + red[5] + red[6] + red[7];
  if (tid < SEQ) weights[tid] = e / tot;
  __syncthreads();

  // ---- phase 5: weighted interest pooling ----
  if (lane < 32) {
    const int k2 = lane;
    float ax = 0.0f, ay = 0.0f;
    for (int s = wave * 50; s < wave * 50 + 50; ++s) {
      const float ws = weights[s];
      const half2_t hv = hP[k2 * SPAD2 + s];
      ax += ws * (float)hv.x;
      ay += ws * (float)hv.y;
    }
    interest_part[wave][2 * k2 + 0] = ax;
    interest_part[wave][2 * k2 + 1] = ay;
  }
  __syncthreads();
  if (tid < EMBED) {
    mlp_in[tid] = interest_part[0][tid] + interest_part[1][tid]
                + interest_part[2][tid] + interest_part[3][tid];
    mlp_in[EMBED + tid] = t_s[tid];
  }
  __syncthreads();

  // ---- phase 6: prediction head ----
  {
    const int j = tid;
    float acc2 = mlp_b1[j];
    #pragma unroll 8
    for (int k = 0; k < 2 * EMBED; ++k)
      acc2 += mlp_in[k] * mlp_w1[k * HIDDEN + j];
    float p2 = fmaxf(acc2, 0.0f) * mlp_w2[j];
    #pragma unroll
    for (int off = 32; off; off >>= 1) p2 += __shfl_xor(p2, off, 64);
    if (lane == 0) red[wave] = p2;
  }
  __syncthreads();
  if (tid == 0) {
    const float z = red[0] + red[1] + red[2] + red[3] + mlp_b2[0];
    out[b] = 1.0f / (1.0f + expf(-z));
  }
}

extern "C" void kernel_launch(void* const* d_in, const int* in_sizes, int n_in,
                              void* d_out, int out_size, void* d_ws, size_t ws_size,
                              hipStream_t stream) {
  const int*   user_hist   = (const int*)  d_in[0];
  const int*   target_item = (const int*)  d_in[1];
  const float* user_emb    = (const float*)d_in[2];
  const float* item_emb    = (const float*)d_in[3];
  const float* attn_w1     = (const float*)d_in[4];
  const float* attn_b1     = (const float*)d_in[5];
  const float* attn_w2     = (const float*)d_in[6];
  // d_in[7] = attn_b2: constant shift on logits -> cancels in softmax
  const float* mlp_w1      = (const float*)d_in[8];
  const float* mlp_b1      = (const float*)d_in[9];
  const float* mlp_w2      = (const float*)d_in[10];
  const float* mlp_b2      = (const float*)d_in[11];
  float* out = (float*)d_out;

  const int batch = in_sizes[1];   // target_item has BATCH elements
  din_fused_kernel<<<batch, 256, 0, stream>>>(
      user_hist, target_item, user_emb, item_emb,
      attn_w1, attn_b1, attn_w2,
      mlp_w1, mlp_b1, mlp_w2, mlp_b2, out);
}

// Round 3
// 230.432 us; speedup vs baseline: 101.1245x; 2.2231x over previous
//
#include <hip/hip_runtime.h>
#include <math.h>

#define EMBED   64
#define HIDDEN  256
#define SEQ     200
#define SEQP    208          // padded to 13 M-tiles of 16
#define MT      13           // M-tiles
#define KCH     4            // K=128 -> 4 chunks of 32 (0-1: h, 2-3: h*t)

typedef _Float16 f16x8 __attribute__((ext_vector_type(8)));
typedef _Float16 f16x4 __attribute__((ext_vector_type(4)));
typedef float    f32x4 __attribute__((ext_vector_type(4)));

// ---------------- precompute: batch-invariant weight transforms ----------------
// ws[0      .. 64KB): Bcat fragment-ordered f16: B'[k][n], k 0-63 = W0+W2, 64-127 = W3
//                     frag slot (nt,chunk,lane) holds B'[chunk*32+(lane>>4)*8+j][nt*16+(lane&15)]
// ws[64KB .. 128KB): D fp32 [64][256] = W1 - W2 (row-major, same as attn_w1)
__global__ void din_precompute(const float* __restrict__ attn_w1, _Float16* __restrict__ fragB,
                               float* __restrict__ Dmat) {
  const int gid = blockIdx.x * 256 + threadIdx.x;   // [0, 8192)
  if (gid < 4096) {
    const int nt = gid >> 8, chunk = (gid >> 6) & 3, lane = gid & 63;
    const int n = nt * 16 + (lane & 15);
    const int kbase = chunk * 32 + (lane >> 4) * 8;
    #pragma unroll
    for (int j = 0; j < 8; ++j) {
      const int k = kbase + j;
      float v;
      if (k < 64) v = attn_w1[k * HIDDEN + n] + attn_w1[(128 + k) * HIDDEN + n];
      else        v = attn_w1[(192 + (k - 64)) * HIDDEN + n];
      fragB[gid * 8 + j] = (_Float16)v;
    }
  } else {
    const int f = (gid - 4096) * 4;                 // 4 floats per thread, 16384 total
    const int k = f >> 8, n = f & 255;
    #pragma unroll
    for (int i = 0; i < 4; ++i)
      Dmat[f + i] = attn_w1[(64 + k) * HIDDEN + n + i] - attn_w1[(128 + k) * HIDDEN + n + i];
  }
}

// ---------------- main fused kernel: one block per batch row ----------------
__global__ __launch_bounds__(256, 3)
void din_fused_kernel(const int* __restrict__ user_hist,
                      const int* __restrict__ target_item,
                      const float* __restrict__ user_emb,
                      const float* __restrict__ item_emb,
                      const float* __restrict__ attn_b1,
                      const float* __restrict__ attn_w2,
                      const float* __restrict__ mlp_w1,
                      const float* __restrict__ mlp_b1,
                      const float* __restrict__ mlp_w2,
                      const float* __restrict__ mlp_b2,
                      const _Float16* __restrict__ fragB,
                      const float* __restrict__ Dmat,
                      float* __restrict__ out)
{
  // h history in A-fragment order: Af[(mt*2+c)*64 + lane][8], (s,k): mt=s>>4, c=k>>5,
  // lane=(s&15)+16*((k>>3)&3), j=k&7
  __shared__ __align__(16) _Float16 Af[MT * 2 * 64 * 8];   // 26624 B
  __shared__ float  t_s[EMBED];
  __shared__ __align__(16) _Float16 t16[EMBED];
  __shared__ float  cl[HIDDEN];
  __shared__ float  lp[4][SEQP];                           // per-wave partial logits
  __shared__ float  weights[SEQP];
  __shared__ float  red[8];
  __shared__ float  ip[4][EMBED];                          // per-wave partial interest
  __shared__ float  mlp_in[2 * EMBED];

  const int b    = blockIdx.x;
  const int tid  = threadIdx.x;
  const int lane = tid & 63;
  const int wave = tid >> 6;
  const int m    = lane & 15;
  const int quad = lane >> 4;

  // ---- phase 0: target embedding ----
  if (tid < EMBED) {
    const float v = item_emb[target_item[b] * EMBED + tid];
    t_s[tid] = v;
    t16[tid] = (_Float16)v;
  }
  __syncthreads();

  // ---- phase 1: gather h into A-fragment LDS (f16), zero pad rows 200..207 ----
  {
    const int* hist = user_hist + b * SEQ;
    #pragma unroll
    for (int it = 0; it < MT; ++it) {                      // 13*256 == 208*16
      const int idx = it * 256 + tid;
      const int s = idx >> 4, q = idx & 15;
      const int k0 = q * 4;
      const int off = (((s >> 4) * 2 + (k0 >> 5)) * 64 + (s & 15) + 16 * ((k0 >> 3) & 3)) * 8 + (k0 & 7);
      f16x4 v;
      if (s < SEQ) {
        const float4 hv = *reinterpret_cast<const float4*>(&user_emb[hist[s] * EMBED + k0]);
        v = f16x4{(_Float16)hv.x, (_Float16)hv.y, (_Float16)hv.z, (_Float16)hv.w};
      } else {
        v = f16x4{(_Float16)0.f, (_Float16)0.f, (_Float16)0.f, (_Float16)0.f};
      }
      *reinterpret_cast<f16x4*>(&Af[off]) = v;
    }
  }

  // ---- phase 2: per-column bias fold c_j = b1_j + t . D[:,j] ----
  {
    float cj = attn_b1[tid];
    #pragma unroll 8
    for (int k = 0; k < EMBED; ++k)
      cj += t_s[k] * Dmat[k * HIDDEN + tid];
    cl[tid] = cj;
  }
  __syncthreads();

  // ---- phase 3: K=128 f16 MFMA GEMM; wave w owns n-tiles 4w..4w+3, B in VGPRs ----
  f16x8 B[4][KCH];
  #pragma unroll
  for (int i = 0; i < 4; ++i)
    #pragma unroll
    for (int c = 0; c < KCH; ++c)
      B[i][c] = reinterpret_cast<const f16x8*>(fragB)[((4 * wave + i) * KCH + c) * 64 + lane];

  const f16x8 tv0 = *reinterpret_cast<const f16x8*>(&t16[quad * 8]);
  const f16x8 tv1 = *reinterpret_cast<const f16x8*>(&t16[32 + quad * 8]);

  float cw[4], w2w[4];
  #pragma unroll
  for (int i = 0; i < 4; ++i) {
    const int n = (4 * wave + i) * 16 + m;
    cw[i]  = cl[n];
    w2w[i] = attn_w2[n];
  }

  for (int mt = 0; mt < MT; ++mt) {
    const f16x8 a0 = *reinterpret_cast<const f16x8*>(&Af[((mt * 2 + 0) * 64 + lane) * 8]);
    const f16x8 a1 = *reinterpret_cast<const f16x8*>(&Af[((mt * 2 + 1) * 64 + lane) * 8]);
    const f16x8 h0 = a0 * tv0;      // (h*t) A-extension, v_pk_mul_f16
    const f16x8 h1 = a1 * tv1;
    float part[4] = {0.f, 0.f, 0.f, 0.f};
    #pragma unroll
    for (int i = 0; i < 4; ++i) {
      f32x4 acc = {0.f, 0.f, 0.f, 0.f};
      acc = __builtin_amdgcn_mfma_f32_16x16x32_f16(a0, B[i][0], acc, 0, 0, 0);
      acc = __builtin_amdgcn_mfma_f32_16x16x32_f16(a1, B[i][1], acc, 0, 0, 0);
      acc = __builtin_amdgcn_mfma_f32_16x16x32_f16(h0, B[i][2], acc, 0, 0, 0);
      acc = __builtin_amdgcn_mfma_f32_16x16x32_f16(h1, B[i][3], acc, 0, 0, 0);
      #pragma unroll
      for (int r = 0; r < 4; ++r)
        part[r] += fmaxf(acc[r] + cw[i], 0.0f) * w2w[i];
    }
    // reduce over the 16 column-lanes (n) within each quad group
    #pragma unroll
    for (int r = 0; r < 4; ++r) {
      float p = part[r];
      p += __shfl_xor(p, 1, 64);
      p += __shfl_xor(p, 2, 64);
      p += __shfl_xor(p, 4, 64);
      p += __shfl_xor(p, 8, 64);
      if (m == 0) {
        const int s = mt * 16 + quad * 4 + r;      // C/D: row = quad*4 + reg
        if (s < SEQ) lp[wave][s] = p;
      }
    }
  }
  __syncthreads();

  // ---- phase 4: softmax over SEQ (attn_b2 cancels) ----
  float v = -INFINITY;
  if (tid < SEQ) v = lp[0][tid] + lp[1][tid] + lp[2][tid] + lp[3][tid];
  float mx = v;
  #pragma unroll
  for (int off = 32; off; off >>= 1) mx = fmaxf(mx, __shfl_xor(mx, off, 64));
  if (lane == 0) red[wave] = mx;
  __syncthreads();
  mx = fmaxf(fmaxf(red[0], red[1]), fmaxf(red[2], red[3]));
  float e = (tid < SEQ) ? expf(v - mx) : 0.0f;
  float ssum = e;
  #pragma unroll
  for (int off = 32; off; off >>= 1) ssum += __shfl_xor(ssum, off, 64);
  if (lane == 0) red[4 + wave] = ssum;
  __syncthreads();
  const float tot = red[4] + red[5] + red[6] + red[7];
  if (tid < SEQP) weights[tid] = (tid < SEQ) ? e / tot : 0.0f;
  __syncthreads();

  // ---- phase 5: weighted interest pooling from A-fragments ----
  {
    float pk[16];
    #pragma unroll
    for (int i = 0; i < 16; ++i) pk[i] = 0.f;
    for (int mt = wave; mt < MT; mt += 4) {
      const f16x8 a0 = *reinterpret_cast<const f16x8*>(&Af[((mt * 2 + 0) * 64 + lane) * 8]);
      const f16x8 a1 = *reinterpret_cast<const f16x8*>(&Af[((mt * 2 + 1) * 64 + lane) * 8]);
      const float wt = weights[mt * 16 + m];
      #pragma unroll
      for (int j = 0; j < 8; ++j) {
        pk[j]     += wt * (float)a0[j];
        pk[8 + j] += wt * (float)a1[j];
      }
    }
    #pragma unroll
    for (int i = 0; i < 16; ++i) {
      float p = pk[i];
      p += __shfl_xor(p, 1, 64);
      p += __shfl_xor(p, 2, 64);
      p += __shfl_xor(p, 4, 64);
      p += __shfl_xor(p, 8, 64);
      pk[i] = p;
    }
    if (m == 0) {
      #pragma unroll
      for (int i = 0; i < 16; ++i) {
        const int k = (i >> 3) * 32 + quad * 8 + (i & 7);
        ip[wave][k] = pk[i];
      }
    }
  }
  __syncthreads();
  if (tid < EMBED)
    mlp_in[tid] = ip[0][tid] + ip[1][tid] + ip[2][tid] + ip[3][tid];
  else if (tid < 2 * EMBED)
    mlp_in[tid] = t_s[tid - EMBED];
  __syncthreads();

  // ---- phase 6: prediction head ----
  {
    float acc2 = mlp_b1[tid];
    #pragma unroll 8
    for (int k = 0; k < 2 * EMBED; ++k)
      acc2 += mlp_in[k] * mlp_w1[k * HIDDEN + tid];
    float p2 = fmaxf(acc2, 0.0f) * mlp_w2[tid];
    #pragma unroll
    for (int off = 32; off; off >>= 1) p2 += __shfl_xor(p2, off, 64);
    if (lane == 0) red[wave] = p2;
  }
  __syncthreads();
  if (tid == 0) {
    const float z = red[0] + red[1] + red[2] + red[3] + mlp_b2[0];
    out[b] = 1.0f / (1.0f + expf(-z));
  }
}

extern "C" void kernel_launch(void* const* d_in, const int* in_sizes, int n_in,
                              void* d_out, int out_size, void* d_ws, size_t ws_size,
                              hipStream_t stream) {
  const int*   user_hist   = (const int*)  d_in[0];
  const int*   target_item = (const int*)  d_in[1];
  const float* user_emb    = (const float*)d_in[2];
  const float* item_emb    = (const float*)d_in[3];
  const float* attn_w1     = (const float*)d_in[4];
  const float* attn_b1     = (const float*)d_in[5];
  const float* attn_w2     = (const float*)d_in[6];
  // d_in[7] = attn_b2: constant shift on logits -> cancels in softmax
  const float* mlp_w1      = (const float*)d_in[8];
  const float* mlp_b1      = (const float*)d_in[9];
  const float* mlp_w2      = (const float*)d_in[10];
  const float* mlp_b2      = (const float*)d_in[11];
  float* out = (float*)d_out;

  _Float16* fragB = (_Float16*)d_ws;                        // 64 KB
  float*    Dmat  = (float*)((char*)d_ws + 65536);          // 64 KB

  din_precompute<<<32, 256, 0, stream>>>(attn_w1, fragB, Dmat);

  const int batch = in_sizes[1];
  din_fused_kernel<<<batch, 256, 0, stream>>>(
      user_hist, target_item, user_emb, item_emb,
      attn_b1, attn_w2, mlp_w1, mlp_b1, mlp_w2, mlp_b2,
      fragB, Dmat, out);
}